// Round 1
// baseline (534.845 us; speedup 1.0000x reference)
//
#include <hip/hip_runtime.h>
#include <math.h>

#define LEVEL 16
#define RED_BLOCKS 2048
#define RED_THREADS 256

// ---------------- Kernel 1: per-column sum over t, |.|, block-partial double sums
__global__ __launch_bounds__(RED_THREADS) void colsum_abs_partial(
    const float4* __restrict__ x, double* __restrict__ partial, int M4)
{
    int tid = blockIdx.x * blockDim.x + threadIdx.x;
    int nthreads = gridDim.x * blockDim.x;

    double acc = 0.0;
    for (int m = tid; m < M4; m += nthreads) {
        float sx = 0.f, sy = 0.f, sz = 0.f, sw = 0.f;
        #pragma unroll
        for (int t = 0; t < LEVEL; ++t) {
            float4 v = x[(size_t)t * M4 + m];
            sx += v.x; sy += v.y; sz += v.z; sw += v.w;
        }
        acc += (double)fabsf(sx) + (double)fabsf(sy)
             + (double)fabsf(sz) + (double)fabsf(sw);
    }

    // wave (64-lane) shuffle reduce in double
    for (int off = 32; off > 0; off >>= 1)
        acc += __shfl_down(acc, off, 64);

    __shared__ double wsum[RED_THREADS / 64];
    int lane = threadIdx.x & 63;
    int wid  = threadIdx.x >> 6;
    if (lane == 0) wsum[wid] = acc;
    __syncthreads();
    if (threadIdx.x == 0) {
        double b = 0.0;
        #pragma unroll
        for (int w = 0; w < RED_THREADS / 64; ++w) b += wsum[w];
        partial[blockIdx.x] = b;
    }
}

// ---------------- Kernel 2: reduce partials -> v_th (f32, reference rounding on final ops)
__global__ __launch_bounds__(256) void finalize_vth(
    const double* __restrict__ partial, float* __restrict__ vth_out, int nb, int Mtotal)
{
    __shared__ double sdata[256];
    double a = 0.0;
    for (int i = threadIdx.x; i < nb; i += blockDim.x) a += partial[i];
    sdata[threadIdx.x] = a;
    __syncthreads();
    for (int s = 128; s > 0; s >>= 1) {
        if (threadIdx.x < s) sdata[threadIdx.x] += sdata[threadIdx.x + s];
        __syncthreads();
    }
    if (threadIdx.x == 0) {
        float mean = (float)(sdata[0] / (double)Mtotal);
        vth_out[0] = mean * 2.0f / sqrtf(15.0f);
    }
}

// ---------------- Kernel 3: 16-step BIF scan, one thread per 4 columns
__global__ __launch_bounds__(256) void bif_scan(
    const float4* __restrict__ x, float4* __restrict__ out,
    const float* __restrict__ vth_p, int M4)
{
    int m = blockIdx.x * blockDim.x + threadIdx.x;
    if (m >= M4) return;

    const float vth = vth_p[0];

    // Issue all 16 loads up front for memory-level parallelism
    float4 xv[LEVEL];
    #pragma unroll
    for (int t = 0; t < LEVEL; ++t)
        xv[t] = x[(size_t)t * M4 + m];

    float v[4], T[4];
    #pragma unroll
    for (int c = 0; c < 4; ++c) { v[c] = 0.5f * vth; T[c] = 0.f; }

    #pragma unroll
    for (int t = 0; t < LEVEL; ++t) {
        float in[4] = { xv[t].x, xv[t].y, xv[t].z, xv[t].w };
        float o[4];
        #pragma unroll
        for (int c = 0; c < 4; ++c) {
            float vv = v[c] + in[c];
            // literal reference forms: (v - v_th >= 0), (T - 15 < 0), (v < 0), (T - 0 > 0)
            bool pos = ((vv - vth) >= 0.f) && ((T[c] - 15.f) < 0.f);
            bool neg = (vv < 0.f) && (T[c] > 0.f);
            float spike = neg ? -1.f : (pos ? 1.f : 0.f);
            vv -= vth * spike;
            T[c] += spike;
            v[c] = vv;
            o[c] = spike * vth;
        }
        float4 ov = make_float4(o[0], o[1], o[2], o[3]);
        out[(size_t)t * M4 + m] = ov;
    }
}

extern "C" void kernel_launch(void* const* d_in, const int* in_sizes, int n_in,
                              void* d_out, int out_size, void* d_ws, size_t ws_size,
                              hipStream_t stream)
{
    const float* x = (const float*)d_in[0];
    float* out = (float*)d_out;
    const int total = in_sizes[0];          // 32*2048*1024 = 67,108,864
    const int M = total / LEVEL;            // 4,194,304 columns
    const int M4 = M / 4;                   // 1,048,576 float4 columns

    double* partials = (double*)d_ws;                       // RED_BLOCKS doubles
    float* vth = (float*)((char*)d_ws + RED_BLOCKS * sizeof(double));

    colsum_abs_partial<<<RED_BLOCKS, RED_THREADS, 0, stream>>>(
        (const float4*)x, partials, M4);

    finalize_vth<<<1, 256, 0, stream>>>(partials, vth, RED_BLOCKS, M);

    int blocks = (M4 + 255) / 256;
    bif_scan<<<blocks, 256, 0, stream>>>(
        (const float4*)x, (float4*)out, vth, M4);
}

// Round 2
// 491.607 us; speedup vs baseline: 1.0880x; 1.0880x over previous
//
#include <hip/hip_runtime.h>
#include <math.h>

#define LEVEL 16
#define RED_BLOCKS 2048
#define RED_THREADS 256

typedef float f32x4 __attribute__((ext_vector_type(4)));

// ---------------- Kernel 1: per-column sum over t, |.|, block-partial double sums
// Regular (caching) loads: we WANT x resident in L3 for the scan kernel's re-read.
__global__ __launch_bounds__(RED_THREADS) void colsum_abs_partial(
    const f32x4* __restrict__ x, double* __restrict__ partial, int M4)
{
    int tid = blockIdx.x * blockDim.x + threadIdx.x;
    int nthreads = gridDim.x * blockDim.x;

    double acc = 0.0;
    for (int m = tid; m < M4; m += nthreads) {
        float sx = 0.f, sy = 0.f, sz = 0.f, sw = 0.f;
        #pragma unroll
        for (int t = 0; t < LEVEL; ++t) {
            f32x4 v = x[(size_t)t * M4 + m];
            sx += v.x; sy += v.y; sz += v.z; sw += v.w;
        }
        acc += (double)fabsf(sx) + (double)fabsf(sy)
             + (double)fabsf(sz) + (double)fabsf(sw);
    }

    // wave (64-lane) shuffle reduce in double
    for (int off = 32; off > 0; off >>= 1)
        acc += __shfl_down(acc, off, 64);

    __shared__ double wsum[RED_THREADS / 64];
    int lane = threadIdx.x & 63;
    int wid  = threadIdx.x >> 6;
    if (lane == 0) wsum[wid] = acc;
    __syncthreads();
    if (threadIdx.x == 0) {
        double b = 0.0;
        #pragma unroll
        for (int w = 0; w < RED_THREADS / 64; ++w) b += wsum[w];
        partial[blockIdx.x] = b;
    }
}

// ---------------- Kernel 2: reduce partials -> v_th (f32, reference rounding on final ops)
__global__ __launch_bounds__(256) void finalize_vth(
    const double* __restrict__ partial, float* __restrict__ vth_out, int nb, int Mtotal)
{
    __shared__ double sdata[256];
    double a = 0.0;
    for (int i = threadIdx.x; i < nb; i += blockDim.x) a += partial[i];
    sdata[threadIdx.x] = a;
    __syncthreads();
    for (int s = 128; s > 0; s >>= 1) {
        if (threadIdx.x < s) sdata[threadIdx.x] += sdata[threadIdx.x + s];
        __syncthreads();
    }
    if (threadIdx.x == 0) {
        float mean = (float)(sdata[0] / (double)Mtotal);
        vth_out[0] = mean * 2.0f / sqrtf(15.0f);
    }
}

// ---------------- Kernel 3: 16-step BIF scan, one thread per 4 columns
// Reversed block order: colsum grid-strides m forward, so high-m x lines are the
// freshest in the 256 MiB L3 — read those first for maximum L3 hit rate.
// Non-temporal loads (last use of x; don't evict unread x lines on miss) and
// non-temporal stores (out is write-once; don't let it evict x from L3).
__global__ __launch_bounds__(256) void bif_scan(
    const f32x4* __restrict__ x, f32x4* __restrict__ out,
    const float* __restrict__ vth_p, int M4)
{
    int bid = gridDim.x - 1 - blockIdx.x;
    int m = bid * blockDim.x + threadIdx.x;
    if (m >= M4) return;

    const float vth = vth_p[0];

    // Issue all 16 loads up front for memory-level parallelism
    f32x4 xv[LEVEL];
    #pragma unroll
    for (int t = 0; t < LEVEL; ++t)
        xv[t] = __builtin_nontemporal_load(&x[(size_t)t * M4 + m]);

    float v[4], T[4];
    #pragma unroll
    for (int c = 0; c < 4; ++c) { v[c] = 0.5f * vth; T[c] = 0.f; }

    #pragma unroll
    for (int t = 0; t < LEVEL; ++t) {
        float in[4] = { xv[t].x, xv[t].y, xv[t].z, xv[t].w };
        f32x4 ov;
        #pragma unroll
        for (int c = 0; c < 4; ++c) {
            float vv = v[c] + in[c];
            // literal reference forms: (v - v_th >= 0), (T - 15 < 0), (v < 0), (T - 0 > 0)
            bool pos = ((vv - vth) >= 0.f) && ((T[c] - 15.f) < 0.f);
            bool neg = (vv < 0.f) && (T[c] > 0.f);
            float spike = neg ? -1.f : (pos ? 1.f : 0.f);
            vv -= vth * spike;
            T[c] += spike;
            v[c] = vv;
            ov[c] = spike * vth;
        }
        __builtin_nontemporal_store(ov, &out[(size_t)t * M4 + m]);
    }
}

extern "C" void kernel_launch(void* const* d_in, const int* in_sizes, int n_in,
                              void* d_out, int out_size, void* d_ws, size_t ws_size,
                              hipStream_t stream)
{
    const float* x = (const float*)d_in[0];
    float* out = (float*)d_out;
    const int total = in_sizes[0];          // 32*2048*1024 = 67,108,864
    const int M = total / LEVEL;            // 4,194,304 columns
    const int M4 = M / 4;                   // 1,048,576 float4 columns

    double* partials = (double*)d_ws;                       // RED_BLOCKS doubles
    float* vth = (float*)((char*)d_ws + RED_BLOCKS * sizeof(double));

    colsum_abs_partial<<<RED_BLOCKS, RED_THREADS, 0, stream>>>(
        (const f32x4*)x, partials, M4);

    finalize_vth<<<1, 256, 0, stream>>>(partials, vth, RED_BLOCKS, M);

    int blocks = (M4 + 255) / 256;
    bif_scan<<<blocks, 256, 0, stream>>>(
        (const f32x4*)x, (f32x4*)out, vth, M4);
}